// Round 17
// baseline (83.440 us; speedup 1.0000x reference)
//
#include <hip/hip_runtime.h>
#include <hip/hip_bf16.h>

#define D_FEAT 32
#define BUCKET_SHIFT 7
#define BUCKET_NODES 128           // 1 << BUCKET_SHIFT
#define MAX_NB 1024                // max buckets
#define CHUNK_E 8192               // edges per sort chunk (62KB LDS in scatter)
#define REC_CHUNK 4096             // records staged per aggregate chunk (=1024*4)

typedef __attribute__((ext_vector_type(8))) unsigned short u16x8;
typedef __attribute__((ext_vector_type(8))) float f32x8;

// round-to-nearest-even f32 -> bf16 bits
static __device__ __forceinline__ unsigned short f2bf(float x) {
    unsigned int u = __float_as_uint(x);
    u += 0x7FFFu + ((u >> 16) & 1u);
    return (unsigned short)(u >> 16);
}
static __device__ __forceinline__ float bf2f(unsigned short b) {
    return __uint_as_float((unsigned int)b << 16);
}

// ---------------------------------------------------------------------------
// K0 (fused): blocks [0, nchunk) do the per-chunk bucket histogram (int4
// vectorized); blocks [nchunk, ...) do prep (inv_norm + bf16 row compress).
// Block 0 also zeroes the region-allocator counter used by col_prefix.
// ---------------------------------------------------------------------------
__global__ __launch_bounds__(256) void prep_hist_kernel(
    const float* __restrict__ feat,
    unsigned short* __restrict__ nfb,
    float* __restrict__ inv_norm,
    const int* __restrict__ dst,
    int* __restrict__ chunk_hist,
    int* __restrict__ alloc,
    int n_nodes, int n_edges, int nb, int nchunk) {

    __shared__ int s_h[MAX_NB];
    int bid = blockIdx.x;
    int t = threadIdx.x;

    if (bid == 0 && t == 0) *alloc = 0;

    if (bid < nchunk) {
        for (int i = t; i < MAX_NB; i += 256) s_h[i] = 0;
        __syncthreads();
        int base = bid * CHUNK_E;
        int cnt = min(CHUNK_E, n_edges - base);
        int cnt4 = cnt >> 2;
        const int4* dst4 = reinterpret_cast<const int4*>(dst + base);
        for (int k = t; k < cnt4; k += 256) {
            int4 d4 = dst4[k];
            atomicAdd(&s_h[d4.x >> BUCKET_SHIFT], 1);
            atomicAdd(&s_h[d4.y >> BUCKET_SHIFT], 1);
            atomicAdd(&s_h[d4.z >> BUCKET_SHIFT], 1);
            atomicAdd(&s_h[d4.w >> BUCKET_SHIFT], 1);
        }
        for (int k = (cnt4 << 2) + t; k < cnt; k += 256)
            atomicAdd(&s_h[dst[base + k] >> BUCKET_SHIFT], 1);
        __syncthreads();
        for (int i = t; i < nb; i += 256)
            chunk_hist[(size_t)i * nchunk + bid] = s_h[i];
    } else {
        int g = (bid - nchunk) * 256 + t;
        int node = g >> 3;
        int lane = g & 7;
        if (node >= n_nodes) return;
        float4 v = reinterpret_cast<const float4*>(feat + (size_t)node * D_FEAT)[lane];
        float ss = v.x * v.x + v.y * v.y + v.z * v.z + v.w * v.w;
        #pragma unroll
        for (int m = 4; m; m >>= 1) ss += __shfl_xor(ss, m, 8);
        if (lane == 0) inv_norm[node] = 1.0f / fmaxf(sqrtf(ss), 1e-12f);
        ushort4 b;
        b.x = f2bf(v.x); b.y = f2bf(v.y); b.z = f2bf(v.z); b.w = f2bf(v.w);
        reinterpret_cast<ushort4*>(nfb + (size_t)node * D_FEAT)[lane] = b;
    }
}

// ---------------------------------------------------------------------------
// S2: per-bucket prefix over chunks — ONE WAVE per bucket — PLUS region
// allocation: bucket_base[wid] = atomicAdd(alloc, total). Region order is
// arbitrary but contents (within-bucket layout) are deterministic, so the
// final output is unchanged. Removes the base_scan kernel entirely.
// ---------------------------------------------------------------------------
__global__ void col_prefix_kernel(int* __restrict__ chunk_hist,
                                  int* __restrict__ total,
                                  int* __restrict__ bucket_base,
                                  int* __restrict__ alloc,
                                  int nchunk, int nb) {
    int wid  = (blockIdx.x * blockDim.x + threadIdx.x) >> 6;
    int lane = threadIdx.x & 63;
    if (wid >= nb) return;
    int* row = chunk_hist + (size_t)wid * nchunk;
    int run = 0;
    for (int base = 0; base < nchunk; base += 64) {
        int c = base + lane;
        int v = (c < nchunk) ? row[c] : 0;
        int incl = v;
        #pragma unroll
        for (int off = 1; off < 64; off <<= 1) {
            int n = __shfl_up(incl, off, 64);
            if (lane >= off) incl += n;
        }
        if (c < nchunk) row[c] = run + (incl - v);   // exclusive within bucket
        run += __shfl(incl, 63, 64);                 // carry (uniform)
    }
    if (lane == 0) {
        total[wid] = run;
        bucket_base[wid] = atomicAdd(alloc, run);
    }
}

// ---------------------------------------------------------------------------
// S4: scatter @512 threads. Per chunk (8192 edges): LDS counting sort by
// bucket (int4 index reads), copy runs to precomputed global slots.
// Zero global atomics. LDS ~62KB.
// ---------------------------------------------------------------------------
__global__ __launch_bounds__(512) void scatter_kernel(const int* __restrict__ src,
                                                      const int* __restrict__ dst,
                                                      const int* __restrict__ chunk_hist,
                                                      const int* __restrict__ bucket_base,
                                                      int* __restrict__ recs,
                                                      int n_edges, int nb, int nchunk) {
    __shared__ int s_cur[MAX_NB];
    __shared__ int s_off[MAX_NB + 1];
    __shared__ int s_gbase[MAX_NB];
    __shared__ int s_sum[512];
    __shared__ int s_rec[CHUNK_E];
    __shared__ unsigned short s_b[CHUNK_E];

    int c = blockIdx.x;
    int t = threadIdx.x;
    int base = c * CHUNK_E;
    int cnt = min(CHUNK_E, n_edges - base);
    int cnt4 = cnt >> 2;
    const int4* dst4 = reinterpret_cast<const int4*>(dst + base);
    const int4* src4 = reinterpret_cast<const int4*>(src + base);

    for (int i = t; i < MAX_NB; i += 512) s_cur[i] = 0;
    __syncthreads();
    for (int k = t; k < cnt4; k += 512) {
        int4 d4 = dst4[k];
        atomicAdd(&s_cur[d4.x >> BUCKET_SHIFT], 1);
        atomicAdd(&s_cur[d4.y >> BUCKET_SHIFT], 1);
        atomicAdd(&s_cur[d4.z >> BUCKET_SHIFT], 1);
        atomicAdd(&s_cur[d4.w >> BUCKET_SHIFT], 1);
    }
    for (int k = (cnt4 << 2) + t; k < cnt; k += 512)
        atomicAdd(&s_cur[dst[base + k] >> BUCKET_SHIFT], 1);
    __syncthreads();

    // exclusive scan of s_cur[1024] -> s_off (2 items/thread, 512 threads)
    int i0 = t * 2;
    int a0 = s_cur[i0], a1 = s_cur[i0 + 1];
    int tsum = a0 + a1;
    s_sum[t] = tsum;
    __syncthreads();
    for (int off = 1; off < 512; off <<= 1) {
        int add = (t >= off) ? s_sum[t - off] : 0;
        __syncthreads();
        s_sum[t] += add;
        __syncthreads();
    }
    int run = s_sum[t] - tsum;
    s_off[i0] = run;
    s_off[i0 + 1] = run + a0;
    if (t == 511) s_off[MAX_NB] = run + tsum;  // == cnt
    __syncthreads();
    for (int i = t; i < MAX_NB; i += 512) s_cur[i] = s_off[i];
    for (int i = t; i < nb; i += 512)
        s_gbase[i] = bucket_base[i] + chunk_hist[(size_t)i * nchunk + c];
    __syncthreads();

    for (int k = t; k < cnt4; k += 512) {
        int4 d4 = dst4[k];
        int4 s4 = src4[k];
        #pragma unroll
        for (int j = 0; j < 4; ++j) {
            int d = (j == 0) ? d4.x : (j == 1) ? d4.y : (j == 2) ? d4.z : d4.w;
            int s = (j == 0) ? s4.x : (j == 1) ? s4.y : (j == 2) ? s4.z : s4.w;
            int bb = d >> BUCKET_SHIFT;
            int lpos = atomicAdd(&s_cur[bb], 1);
            s_rec[lpos] = (s << BUCKET_SHIFT) | (d & (BUCKET_NODES - 1));
            s_b[lpos] = (unsigned short)bb;
        }
    }
    for (int k = (cnt4 << 2) + t; k < cnt; k += 512) {
        int d = dst[base + k];
        int s = src[base + k];
        int bb = d >> BUCKET_SHIFT;
        int lpos = atomicAdd(&s_cur[bb], 1);
        s_rec[lpos] = (s << BUCKET_SHIFT) | (d & (BUCKET_NODES - 1));
        s_b[lpos] = (unsigned short)bb;
    }
    __syncthreads();

    for (int i = t; i < cnt; i += 512) {
        int bb = s_b[i];
        recs[s_gbase[bb] + (i - s_off[bb])] = s_rec[i];
    }
}

// ---------------------------------------------------------------------------
// C v7: TWO blocks per bucket, 1024 thr = 256 groups x 4 lanes. Each block
// owns 64 nodes; each node's run is split across FOUR groups (sub = g>>6,
// records rs+sub, step 4) -> serial chain ~4 with 2-deep prefetch. Records
// reg-staged once (4/thread, stride-1024). Partials from subs 1..3 combined
// via LDS; sub 0 reduces and does the single coalesced row write.
// LDS ~44.6 KB; ~2 blocks/CU.
// ---------------------------------------------------------------------------
__global__ __launch_bounds__(1024) void bucket_aggregate_kernel(
    const unsigned short* __restrict__ nfb,
    const float* __restrict__ inv_norm,
    const int* __restrict__ bucket_base,
    const int* __restrict__ total,
    const int* __restrict__ recs,
    const float* __restrict__ beta,
    float* __restrict__ out, int n_nodes) {

    __shared__ int s_rec[REC_CHUNK];          // 16 KB
    __shared__ int s_hist[64];
    __shared__ int s_off[65];
    __shared__ float s_part[3][64][36];       // 27.6 KB

    int blk = blockIdx.x;
    int b    = blk >> 1;       // bucket
    int half = blk & 1;        // which 64-node half of the bucket
    int node0 = b * BUCKET_NODES + half * 64;
    int start = bucket_base[b];
    int end   = start + total[b];
    int t = threadIdx.x;
    int group = t >> 2;        // 0..255
    int lane  = t & 3;         // 16B of the 64B row per lane
    int nodeLocal = group & 63;
    int sub = group >> 6;      // 0..3: record subsequence
    float bscale = beta[0];

    int myv = node0 + nodeLocal;
    f32x8 bn;
    f32x8 acc;
    float ssum = 0.f;
    #pragma unroll
    for (int j = 0; j < 8; ++j) { bn[j] = 0.f; acc[j] = 0.f; }
    if (myv < n_nodes) {
        u16x8 braw = reinterpret_cast<const u16x8*>(nfb + (size_t)myv * D_FEAT)[lane];
        float invv = inv_norm[myv];
        #pragma unroll
        for (int j = 0; j < 8; ++j) bn[j] = bf2f(braw[j]) * invv;
    }

    for (int cbase = start; cbase < end; cbase += REC_CHUNK) {
        int cnt = min(REC_CHUNK, end - cbase);

        // single global read of this chunk's records into registers
        int r[4];
        #pragma unroll
        for (int j = 0; j < 4; ++j) {
            int k = t + j * 1024;                // coalesced stride-1024
            r[j] = (k < cnt) ? recs[cbase + k] : -1;
        }

        if (t < 64) s_hist[t] = 0;
        __syncthreads();
        #pragma unroll
        for (int j = 0; j < 4; ++j)
            if (r[j] >= 0) {
                int dl = r[j] & (BUCKET_NODES - 1);
                if ((dl >> 6) == half) atomicAdd(&s_hist[dl & 63], 1);
            }
        __syncthreads();

        // wave-0 shuffle scan of the 64 counters
        if (t < 64) {
            int v = s_hist[t];
            int incl = v;
            #pragma unroll
            for (int off = 1; off < 64; off <<= 1) {
                int n = __shfl_up(incl, off, 64);
                if (t >= off) incl += n;
            }
            s_off[t + 1] = incl;
            if (t == 0) s_off[0] = 0;
            s_hist[t] = incl - v;   // run cursor (exclusive start)
        }
        __syncthreads();

        #pragma unroll
        for (int j = 0; j < 4; ++j)
            if (r[j] >= 0) {
                int dl = r[j] & (BUCKET_NODES - 1);
                if ((dl >> 6) == half) {
                    int pos = atomicAdd(&s_hist[dl & 63], 1);
                    s_rec[pos] = r[j];
                }
            }
        __syncthreads();

        // walk my node's subsequence (records rs+sub, step 4), 2-deep pipeline
        {
            int rs = s_off[nodeLocal];
            int re = s_off[nodeLocal + 1];
            int i = rs + sub;

            int u0 = 0; float inv0 = 0.f;
            u16x8 raw0;
            #pragma unroll
            for (int j = 0; j < 8; ++j) raw0[j] = 0;
            if (i < re) {
                u0 = ((unsigned)s_rec[i]) >> BUCKET_SHIFT;
                inv0 = inv_norm[u0];
                raw0 = reinterpret_cast<const u16x8*>(nfb + (size_t)u0 * D_FEAT)[lane];
            }
            for (; i < re; i += 4) {
                int u1 = 0; float inv1 = 0.f;
                u16x8 raw1;
                #pragma unroll
                for (int j = 0; j < 8; ++j) raw1[j] = 0;
                if (i + 4 < re) {
                    u1 = ((unsigned)s_rec[i + 4]) >> BUCKET_SHIFT;
                    inv1 = inv_norm[u1];
                    raw1 = reinterpret_cast<const u16x8*>(nfb + (size_t)u1 * D_FEAT)[lane];
                }
                f32x8 a;
                float d = 0.f;
                #pragma unroll
                for (int j = 0; j < 8; ++j) {
                    a[j] = bf2f(raw0[j]);
                    d = fmaf(a[j], bn[j], d);
                }
                d += __shfl_xor(d, 1, 4);
                d += __shfl_xor(d, 2, 4);
                float pe = __expf(bscale * d * inv0);  // |arg|<=beta: no max-shift
                #pragma unroll
                for (int j = 0; j < 8; ++j) acc[j] = fmaf(pe, a[j], acc[j]);
                ssum += pe;
                raw0 = raw1; inv0 = inv1;
            }
        }
        __syncthreads();
    }

    // combine partials: subs 1..3 publish, sub 0 reduces + writes
    if (sub != 0) {
        float* p = &s_part[sub - 1][nodeLocal][lane * 8];
        #pragma unroll
        for (int j = 0; j < 8; ++j) p[j] = acc[j];
        if (lane == 0) s_part[sub - 1][nodeLocal][32] = ssum;
    }
    __syncthreads();
    if (sub == 0 && myv < n_nodes) {
        #pragma unroll
        for (int s = 0; s < 3; ++s) {
            const float* p = &s_part[s][nodeLocal][lane * 8];
            #pragma unroll
            for (int j = 0; j < 8; ++j) acc[j] += p[j];
            ssum += s_part[s][nodeLocal][32];
        }
        float inv_s = (ssum > 0.f) ? (1.0f / ssum) : 0.0f;
        float* op = out + (size_t)myv * D_FEAT + lane * 8;
        reinterpret_cast<float4*>(op)[0] =
            make_float4(acc[0] * inv_s, acc[1] * inv_s, acc[2] * inv_s, acc[3] * inv_s);
        reinterpret_cast<float4*>(op)[1] =
            make_float4(acc[4] * inv_s, acc[5] * inv_s, acc[6] * inv_s, acc[7] * inv_s);
    }
}

// ---------------------------------------------------------------------------
// Fallback 1 (proven R6): packed linked-list + bf16 chase.
// ---------------------------------------------------------------------------
__global__ void prep_kernel(const float* __restrict__ feat,
                            unsigned short* __restrict__ nfb,
                            float* __restrict__ inv_norm, int n_nodes) {
    int g = blockIdx.x * blockDim.x + threadIdx.x;
    int node = g >> 3;
    int lane = g & 7;
    if (node >= n_nodes) return;
    float4 v = reinterpret_cast<const float4*>(feat + (size_t)node * D_FEAT)[lane];
    float ss = v.x * v.x + v.y * v.y + v.z * v.z + v.w * v.w;
    #pragma unroll
    for (int m = 4; m; m >>= 1) ss += __shfl_xor(ss, m, 8);
    if (lane == 0) inv_norm[node] = 1.0f / fmaxf(sqrtf(ss), 1e-12f);
    ushort4 b;
    b.x = f2bf(v.x); b.y = f2bf(v.y); b.z = f2bf(v.z); b.w = f2bf(v.w);
    reinterpret_cast<ushort4*>(nfb + (size_t)node * D_FEAT)[lane] = b;
}

__global__ void link_packed_kernel(const int* __restrict__ src,
                                   const int* __restrict__ dst,
                                   int* __restrict__ head,
                                   int2* __restrict__ rec, int n_edges) {
    int stride = gridDim.x * blockDim.x;
    for (int e = blockIdx.x * blockDim.x + threadIdx.x; e < n_edges; e += stride) {
        int d = dst[e];
        int s = src[e];
        int old = atomicExch(&head[d], e);
        rec[e] = make_int2(old, s);
    }
}

__global__ void fused_chase_bf16_kernel(const unsigned short* __restrict__ nfb,
                                        const float* __restrict__ inv_norm,
                                        const int* __restrict__ head,
                                        const int2* __restrict__ rec,
                                        const float* __restrict__ beta,
                                        float* __restrict__ out, int n_nodes) {
    int g = blockIdx.x * blockDim.x + threadIdx.x;
    int node = g >> 2;
    int lane = g & 3;
    if (node >= n_nodes) return;

    float bscale = beta[0];
    float invv = inv_norm[node];
    u16x8 braw = reinterpret_cast<const u16x8*>(nfb + (size_t)node * D_FEAT)[lane];
    f32x8 bn;
    #pragma unroll
    for (int j = 0; j < 8; ++j) bn[j] = bf2f(braw[j]) * invv;

    f32x8 acc;
    #pragma unroll
    for (int j = 0; j < 8; ++j) acc[j] = 0.f;
    float ssum = 0.f;

    int e = head[node];
    while (e >= 0) {
        int2 r = rec[e];
        int en = r.x, u = r.y;
        float invu = inv_norm[u];
        u16x8 araw = reinterpret_cast<const u16x8*>(nfb + (size_t)u * D_FEAT)[lane];
        f32x8 a;
        float d = 0.f;
        #pragma unroll
        for (int j = 0; j < 8; ++j) {
            a[j] = bf2f(araw[j]);
            d = fmaf(a[j], bn[j], d);
        }
        d += __shfl_xor(d, 1, 4);
        d += __shfl_xor(d, 2, 4);
        float pe = __expf(bscale * d * invu);
        #pragma unroll
        for (int j = 0; j < 8; ++j) acc[j] = fmaf(pe, a[j], acc[j]);
        ssum += pe;
        e = en;
    }

    float inv_s = (ssum > 0.f) ? (1.0f / ssum) : 0.0f;
    float* op = out + (size_t)node * D_FEAT + lane * 8;
    reinterpret_cast<float4*>(op)[0] =
        make_float4(acc[0] * inv_s, acc[1] * inv_s, acc[2] * inv_s, acc[3] * inv_s);
    reinterpret_cast<float4*>(op)[1] =
        make_float4(acc[4] * inv_s, acc[5] * inv_s, acc[6] * inv_s, acc[7] * inv_s);
}

// ---------------------------------------------------------------------------
// Fallback 2 (tiny ws): f32 atomic path.
// ---------------------------------------------------------------------------
__global__ void node_invnorm_kernel(const float* __restrict__ feat,
                                    float* __restrict__ inv_norm, int n_nodes) {
    int g = blockIdx.x * blockDim.x + threadIdx.x;
    int node = g >> 3;
    int lane = g & 7;
    if (node >= n_nodes) return;
    float4 v = reinterpret_cast<const float4*>(feat + (size_t)node * D_FEAT)[lane];
    float ss = v.x * v.x + v.y * v.y + v.z * v.z + v.w * v.w;
    #pragma unroll
    for (int m = 4; m; m >>= 1) ss += __shfl_xor(ss, m, 8);
    if (lane == 0) inv_norm[node] = 1.0f / fmaxf(sqrtf(ss), 1e-12f);
}

__global__ void edge_p_kernel(const float* __restrict__ feat,
                              const float* __restrict__ inv_norm,
                              const int* __restrict__ src,
                              const int* __restrict__ dst,
                              const float* __restrict__ beta,
                              float* __restrict__ p, float* __restrict__ s,
                              int n_edges) {
    int g = blockIdx.x * blockDim.x + threadIdx.x;
    int e = g >> 3;
    int lane = g & 7;
    if (e >= n_edges) return;
    int u = src[e];
    int v = dst[e];
    float4 a = reinterpret_cast<const float4*>(feat + (size_t)u * D_FEAT)[lane];
    float4 b = reinterpret_cast<const float4*>(feat + (size_t)v * D_FEAT)[lane];
    float d = a.x * b.x;
    d = fmaf(a.y, b.y, d);
    d = fmaf(a.z, b.z, d);
    d = fmaf(a.w, b.w, d);
    #pragma unroll
    for (int m = 4; m; m >>= 1) d += __shfl_xor(d, m, 8);
    if (lane == 0) {
        float pe = __expf(beta[0] * d * inv_norm[u] * inv_norm[v]);
        p[e] = pe;
        atomicAdd(&s[v], pe);
    }
}

__global__ void aggregate_atomic_kernel(const float* __restrict__ feat,
                                        const int* __restrict__ src,
                                        const int* __restrict__ dst,
                                        const float* __restrict__ p,
                                        const float* __restrict__ s,
                                        float* __restrict__ out, int n_edges) {
    int g = blockIdx.x * blockDim.x + threadIdx.x;
    int e = g >> 5;
    int lane = g & 31;
    if (e >= n_edges) return;
    int u = src[e];
    int v = dst[e];
    float w = p[e] / s[v];
    atomicAdd(&out[(size_t)v * D_FEAT + lane], feat[(size_t)u * D_FEAT + lane] * w);
}

extern "C" void kernel_launch(void* const* d_in, const int* in_sizes, int n_in,
                              void* d_out, int out_size, void* d_ws, size_t ws_size,
                              hipStream_t stream) {
    const float* feat = (const float*)d_in[0];
    const float* beta = (const float*)d_in[1];
    const int*   src  = (const int*)d_in[2];
    const int*   dst  = (const int*)d_in[3];
    float* out = (float*)d_out;

    int n_nodes = in_sizes[0] / D_FEAT;
    int n_edges = in_sizes[2];
    int nb = (n_nodes + BUCKET_NODES - 1) / BUCKET_NODES;
    int nchunk = (n_edges + CHUNK_E - 1) / CHUNK_E;

    size_t nfb_bytes = (size_t)n_nodes * D_FEAT * 2;
    size_t need_sort = nfb_bytes +
                       ((size_t)n_nodes + (nb + 1) + MAX_NB +
                        (size_t)nb * nchunk + (size_t)n_edges) * 4;
    size_t need_ll = nfb_bytes + (size_t)n_nodes * 8 + (size_t)n_edges * 8;

    bool sort_ok = (ws_size >= need_sort) && (nb <= MAX_NB) &&
                   (n_nodes <= (1 << 24));

    if (sort_ok) {
        unsigned short* nfb = (unsigned short*)d_ws;
        float* inv_norm   = (float*)((char*)d_ws + nfb_bytes);
        int* bucket_base  = (int*)(inv_norm + n_nodes);   // [nb] + alloc at [nb]
        int* alloc        = bucket_base + nb;
        int* total        = bucket_base + (nb + 1);
        int* chunk_hist   = total + MAX_NB;
        int* recs         = chunk_hist + (size_t)nb * nchunk;

        {
            int prep_blocks = (n_nodes * 8 + 255) / 256;
            prep_hist_kernel<<<nchunk + prep_blocks, 256, 0, stream>>>(
                feat, nfb, inv_norm, dst, chunk_hist, alloc,
                n_nodes, n_edges, nb, nchunk);
        }
        {
            int blocks = (nb + 3) / 4;
            col_prefix_kernel<<<blocks, 256, 0, stream>>>(
                chunk_hist, total, bucket_base, alloc, nchunk, nb);
        }
        scatter_kernel<<<nchunk, 512, 0, stream>>>(src, dst, chunk_hist, bucket_base,
                                                   recs, n_edges, nb, nchunk);
        bucket_aggregate_kernel<<<nb * 2, 1024, 0, stream>>>(
            nfb, inv_norm, bucket_base, total, recs, beta, out, n_nodes);
    } else if (ws_size >= need_ll) {
        unsigned short* nfb = (unsigned short*)d_ws;
        float* inv_norm = (float*)((char*)d_ws + nfb_bytes);
        int*   head     = (int*)(inv_norm + n_nodes);
        int2*  rec      = (int2*)(head + n_nodes);

        hipMemsetAsync(head, 0xFF, (size_t)n_nodes * sizeof(int), stream);
        {
            int tt = n_nodes * 8;
            prep_kernel<<<(tt + 255) / 256, 256, 0, stream>>>(feat, nfb, inv_norm, n_nodes);
        }
        link_packed_kernel<<<2048, 256, 0, stream>>>(src, dst, head, rec, n_edges);
        {
            int tt = n_nodes * 4;
            fused_chase_bf16_kernel<<<(tt + 255) / 256, 256, 0, stream>>>(
                nfb, inv_norm, head, rec, beta, out, n_nodes);
        }
    } else {
        float* inv_norm = (float*)d_ws;
        float* s_sum    = inv_norm + n_nodes;
        float* p        = s_sum + n_nodes;

        hipMemsetAsync(s_sum, 0, (size_t)n_nodes * sizeof(float), stream);
        hipMemsetAsync(out, 0, (size_t)out_size * sizeof(float), stream);

        {
            int tt = n_nodes * 8;
            node_invnorm_kernel<<<(tt + 255) / 256, 256, 0, stream>>>(feat, inv_norm, n_nodes);
        }
        {
            long long tt = (long long)n_edges * 8;
            edge_p_kernel<<<(int)((tt + 255) / 256), 256, 0, stream>>>(
                feat, inv_norm, src, dst, beta, p, s_sum, n_edges);
        }
        {
            long long tt = (long long)n_edges * 32;
            aggregate_atomic_kernel<<<(int)((tt + 255) / 256), 256, 0, stream>>>(
                feat, src, dst, p, s_sum, out, n_edges);
        }
    }
}

// Round 18
// 71.787 us; speedup vs baseline: 1.1623x; 1.1623x over previous
//
#include <hip/hip_runtime.h>
#include <hip/hip_bf16.h>

#define D_FEAT 32
#define BUCKET_SHIFT 7
#define BUCKET_NODES 128           // 1 << BUCKET_SHIFT
#define MAX_NB 1024                // max buckets
#define CHUNK_E 8192               // edges per sort chunk (62KB LDS in scatter)
#define REC_CHUNK 4096             // records staged per aggregate chunk (=512*8)

typedef __attribute__((ext_vector_type(8))) unsigned short u16x8;
typedef __attribute__((ext_vector_type(8))) float f32x8;

// round-to-nearest-even f32 -> bf16 bits
static __device__ __forceinline__ unsigned short f2bf(float x) {
    unsigned int u = __float_as_uint(x);
    u += 0x7FFFu + ((u >> 16) & 1u);
    return (unsigned short)(u >> 16);
}
static __device__ __forceinline__ float bf2f(unsigned short b) {
    return __uint_as_float((unsigned int)b << 16);
}

// ---------------------------------------------------------------------------
// K0 (fused): blocks [0, nchunk) do the per-chunk bucket histogram (int4
// vectorized); blocks [nchunk, ...) do prep (inv_norm + bf16 row compress).
// Block 0 zeroes the region allocator.
// ---------------------------------------------------------------------------
__global__ __launch_bounds__(256) void prep_hist_kernel(
    const float* __restrict__ feat,
    unsigned short* __restrict__ nfb,
    float* __restrict__ inv_norm,
    const int* __restrict__ dst,
    int* __restrict__ chunk_hist,
    int* __restrict__ alloc,
    int n_nodes, int n_edges, int nb, int nchunk) {

    __shared__ int s_h[MAX_NB];
    int bid = blockIdx.x;
    int t = threadIdx.x;

    if (bid == 0 && t == 0) *alloc = 0;

    if (bid < nchunk) {
        for (int i = t; i < MAX_NB; i += 256) s_h[i] = 0;
        __syncthreads();
        int base = bid * CHUNK_E;
        int cnt = min(CHUNK_E, n_edges - base);
        int cnt4 = cnt >> 2;
        const int4* dst4 = reinterpret_cast<const int4*>(dst + base);
        for (int k = t; k < cnt4; k += 256) {
            int4 d4 = dst4[k];
            atomicAdd(&s_h[d4.x >> BUCKET_SHIFT], 1);
            atomicAdd(&s_h[d4.y >> BUCKET_SHIFT], 1);
            atomicAdd(&s_h[d4.z >> BUCKET_SHIFT], 1);
            atomicAdd(&s_h[d4.w >> BUCKET_SHIFT], 1);
        }
        for (int k = (cnt4 << 2) + t; k < cnt; k += 256)
            atomicAdd(&s_h[dst[base + k] >> BUCKET_SHIFT], 1);
        __syncthreads();
        for (int i = t; i < nb; i += 256)
            chunk_hist[(size_t)i * nchunk + bid] = s_h[i];
    } else {
        int g = (bid - nchunk) * 256 + t;
        int node = g >> 3;
        int lane = g & 7;
        if (node >= n_nodes) return;
        float4 v = reinterpret_cast<const float4*>(feat + (size_t)node * D_FEAT)[lane];
        float ss = v.x * v.x + v.y * v.y + v.z * v.z + v.w * v.w;
        #pragma unroll
        for (int m = 4; m; m >>= 1) ss += __shfl_xor(ss, m, 8);
        if (lane == 0) inv_norm[node] = 1.0f / fmaxf(sqrtf(ss), 1e-12f);
        ushort4 b;
        b.x = f2bf(v.x); b.y = f2bf(v.y); b.z = f2bf(v.z); b.w = f2bf(v.w);
        reinterpret_cast<ushort4*>(nfb + (size_t)node * D_FEAT)[lane] = b;
    }
}

// ---------------------------------------------------------------------------
// S2: per-bucket prefix over chunks — ONE WAVE per bucket — plus region
// allocation: bucket_base[wid] = atomicAdd(alloc, total). Region order is
// arbitrary; within-bucket layout is deterministic, so output is unchanged.
// (base_scan kernel eliminated.)
// ---------------------------------------------------------------------------
__global__ void col_prefix_kernel(int* __restrict__ chunk_hist,
                                  int* __restrict__ total,
                                  int* __restrict__ bucket_base,
                                  int* __restrict__ alloc,
                                  int nchunk, int nb) {
    int wid  = (blockIdx.x * blockDim.x + threadIdx.x) >> 6;
    int lane = threadIdx.x & 63;
    if (wid >= nb) return;
    int* row = chunk_hist + (size_t)wid * nchunk;
    int run = 0;
    for (int base = 0; base < nchunk; base += 64) {
        int c = base + lane;
        int v = (c < nchunk) ? row[c] : 0;
        int incl = v;
        #pragma unroll
        for (int off = 1; off < 64; off <<= 1) {
            int n = __shfl_up(incl, off, 64);
            if (lane >= off) incl += n;
        }
        if (c < nchunk) row[c] = run + (incl - v);   // exclusive within bucket
        run += __shfl(incl, 63, 64);                 // carry (uniform)
    }
    if (lane == 0) {
        total[wid] = run;
        bucket_base[wid] = atomicAdd(alloc, run);
    }
}

// ---------------------------------------------------------------------------
// S4: scatter @512 threads. Per chunk (8192 edges): LDS counting sort by
// bucket (int4 index reads), copy runs to precomputed global slots.
// Zero global atomics. LDS ~62KB.
// ---------------------------------------------------------------------------
__global__ __launch_bounds__(512) void scatter_kernel(const int* __restrict__ src,
                                                      const int* __restrict__ dst,
                                                      const int* __restrict__ chunk_hist,
                                                      const int* __restrict__ bucket_base,
                                                      int* __restrict__ recs,
                                                      int n_edges, int nb, int nchunk) {
    __shared__ int s_cur[MAX_NB];
    __shared__ int s_off[MAX_NB + 1];
    __shared__ int s_gbase[MAX_NB];
    __shared__ int s_sum[512];
    __shared__ int s_rec[CHUNK_E];
    __shared__ unsigned short s_b[CHUNK_E];

    int c = blockIdx.x;
    int t = threadIdx.x;
    int base = c * CHUNK_E;
    int cnt = min(CHUNK_E, n_edges - base);
    int cnt4 = cnt >> 2;
    const int4* dst4 = reinterpret_cast<const int4*>(dst + base);
    const int4* src4 = reinterpret_cast<const int4*>(src + base);

    for (int i = t; i < MAX_NB; i += 512) s_cur[i] = 0;
    __syncthreads();
    for (int k = t; k < cnt4; k += 512) {
        int4 d4 = dst4[k];
        atomicAdd(&s_cur[d4.x >> BUCKET_SHIFT], 1);
        atomicAdd(&s_cur[d4.y >> BUCKET_SHIFT], 1);
        atomicAdd(&s_cur[d4.z >> BUCKET_SHIFT], 1);
        atomicAdd(&s_cur[d4.w >> BUCKET_SHIFT], 1);
    }
    for (int k = (cnt4 << 2) + t; k < cnt; k += 512)
        atomicAdd(&s_cur[dst[base + k] >> BUCKET_SHIFT], 1);
    __syncthreads();

    // exclusive scan of s_cur[1024] -> s_off (2 items/thread, 512 threads)
    int i0 = t * 2;
    int a0 = s_cur[i0], a1 = s_cur[i0 + 1];
    int tsum = a0 + a1;
    s_sum[t] = tsum;
    __syncthreads();
    for (int off = 1; off < 512; off <<= 1) {
        int add = (t >= off) ? s_sum[t - off] : 0;
        __syncthreads();
        s_sum[t] += add;
        __syncthreads();
    }
    int run = s_sum[t] - tsum;
    s_off[i0] = run;
    s_off[i0 + 1] = run + a0;
    if (t == 511) s_off[MAX_NB] = run + tsum;  // == cnt
    __syncthreads();
    for (int i = t; i < MAX_NB; i += 512) s_cur[i] = s_off[i];
    for (int i = t; i < nb; i += 512)
        s_gbase[i] = bucket_base[i] + chunk_hist[(size_t)i * nchunk + c];
    __syncthreads();

    for (int k = t; k < cnt4; k += 512) {
        int4 d4 = dst4[k];
        int4 s4 = src4[k];
        #pragma unroll
        for (int j = 0; j < 4; ++j) {
            int d = (j == 0) ? d4.x : (j == 1) ? d4.y : (j == 2) ? d4.z : d4.w;
            int s = (j == 0) ? s4.x : (j == 1) ? s4.y : (j == 2) ? s4.z : s4.w;
            int bb = d >> BUCKET_SHIFT;
            int lpos = atomicAdd(&s_cur[bb], 1);
            s_rec[lpos] = (s << BUCKET_SHIFT) | (d & (BUCKET_NODES - 1));
            s_b[lpos] = (unsigned short)bb;
        }
    }
    for (int k = (cnt4 << 2) + t; k < cnt; k += 512) {
        int d = dst[base + k];
        int s = src[base + k];
        int bb = d >> BUCKET_SHIFT;
        int lpos = atomicAdd(&s_cur[bb], 1);
        s_rec[lpos] = (s << BUCKET_SHIFT) | (d & (BUCKET_NODES - 1));
        s_b[lpos] = (unsigned short)bb;
    }
    __syncthreads();

    for (int i = t; i < cnt; i += 512) {
        int bb = s_b[i];
        recs[s_gbase[bb] + (i - s_off[bb])] = s_rec[i];
    }
}

// ---------------------------------------------------------------------------
// C v6 (R16 proven geometry): TWO blocks per bucket, 512 thr = 128 groups x
// 4 lanes. Each block owns 64 nodes; each node's run is split across TWO
// groups (even/odd records). Records reg-staged once (8/thread). Partials
// combined via LDS. end = start + total[b] (allocator-based regions).
// ---------------------------------------------------------------------------
__global__ __launch_bounds__(512) void bucket_aggregate_kernel(
    const unsigned short* __restrict__ nfb,
    const float* __restrict__ inv_norm,
    const int* __restrict__ bucket_base,
    const int* __restrict__ total,
    const int* __restrict__ recs,
    const float* __restrict__ beta,
    float* __restrict__ out, int n_nodes) {

    __shared__ int s_rec[REC_CHUNK];          // 16 KB
    __shared__ int s_hist[64];
    __shared__ int s_off[65];
    __shared__ float s_part[64][36];          // 9.2 KB

    int blk = blockIdx.x;
    int b    = blk >> 1;       // bucket
    int half = blk & 1;        // which 64-node half of the bucket
    int node0 = b * BUCKET_NODES + half * 64;
    int start = bucket_base[b];
    int end   = start + total[b];
    int t = threadIdx.x;
    int group = t >> 2;        // 0..127
    int lane  = t & 3;         // 16B of the 64B row per lane
    int nodeLocal = group & 63;
    int sub = group >> 6;      // 0: even records, 1: odd records
    float bscale = beta[0];

    int myv = node0 + nodeLocal;
    f32x8 bn;
    f32x8 acc;
    float ssum = 0.f;
    #pragma unroll
    for (int j = 0; j < 8; ++j) { bn[j] = 0.f; acc[j] = 0.f; }
    if (myv < n_nodes) {
        u16x8 braw = reinterpret_cast<const u16x8*>(nfb + (size_t)myv * D_FEAT)[lane];
        float invv = inv_norm[myv];
        #pragma unroll
        for (int j = 0; j < 8; ++j) bn[j] = bf2f(braw[j]) * invv;
    }

    for (int cbase = start; cbase < end; cbase += REC_CHUNK) {
        int cnt = min(REC_CHUNK, end - cbase);

        // single global read of this chunk's records into registers
        int r[8];
        #pragma unroll
        for (int j = 0; j < 8; ++j) {
            int k = t + j * 512;                 // coalesced stride-512
            r[j] = (k < cnt) ? recs[cbase + k] : -1;
        }

        if (t < 64) s_hist[t] = 0;
        __syncthreads();
        #pragma unroll
        for (int j = 0; j < 8; ++j)
            if (r[j] >= 0) {
                int dl = r[j] & (BUCKET_NODES - 1);
                if ((dl >> 6) == half) atomicAdd(&s_hist[dl & 63], 1);
            }
        __syncthreads();

        // wave-0 shuffle scan of the 64 counters
        if (t < 64) {
            int v = s_hist[t];
            int incl = v;
            #pragma unroll
            for (int off = 1; off < 64; off <<= 1) {
                int n = __shfl_up(incl, off, 64);
                if (t >= off) incl += n;
            }
            s_off[t + 1] = incl;
            if (t == 0) s_off[0] = 0;
            s_hist[t] = incl - v;   // run cursor (exclusive start)
        }
        __syncthreads();

        #pragma unroll
        for (int j = 0; j < 8; ++j)
            if (r[j] >= 0) {
                int dl = r[j] & (BUCKET_NODES - 1);
                if ((dl >> 6) == half) {
                    int pos = atomicAdd(&s_hist[dl & 63], 1);
                    s_rec[pos] = r[j];
                }
            }
        __syncthreads();

        // walk my node's subsequence (records rs+sub, step 2), 2-deep pipeline
        {
            int rs = s_off[nodeLocal];
            int re = s_off[nodeLocal + 1];
            int i = rs + sub;

            int u0 = 0; float inv0 = 0.f;
            u16x8 raw0;
            #pragma unroll
            for (int j = 0; j < 8; ++j) raw0[j] = 0;
            if (i < re) {
                u0 = ((unsigned)s_rec[i]) >> BUCKET_SHIFT;
                inv0 = inv_norm[u0];
                raw0 = reinterpret_cast<const u16x8*>(nfb + (size_t)u0 * D_FEAT)[lane];
            }
            for (; i < re; i += 2) {
                int u1 = 0; float inv1 = 0.f;
                u16x8 raw1;
                #pragma unroll
                for (int j = 0; j < 8; ++j) raw1[j] = 0;
                if (i + 2 < re) {
                    u1 = ((unsigned)s_rec[i + 2]) >> BUCKET_SHIFT;
                    inv1 = inv_norm[u1];
                    raw1 = reinterpret_cast<const u16x8*>(nfb + (size_t)u1 * D_FEAT)[lane];
                }
                f32x8 a;
                float d = 0.f;
                #pragma unroll
                for (int j = 0; j < 8; ++j) {
                    a[j] = bf2f(raw0[j]);
                    d = fmaf(a[j], bn[j], d);
                }
                d += __shfl_xor(d, 1, 4);
                d += __shfl_xor(d, 2, 4);
                float pe = __expf(bscale * d * inv0);  // |arg|<=beta: no max-shift
                #pragma unroll
                for (int j = 0; j < 8; ++j) acc[j] = fmaf(pe, a[j], acc[j]);
                ssum += pe;
                raw0 = raw1; inv0 = inv1;
            }
        }
        __syncthreads();
    }

    // combine sub0 + sub1 partials via LDS, then write
    if (sub == 0) {
        float* p = &s_part[nodeLocal][lane * 8];
        #pragma unroll
        for (int j = 0; j < 8; ++j) p[j] = acc[j];
        if (lane == 0) s_part[nodeLocal][32] = ssum;
    }
    __syncthreads();
    if (sub == 1 && myv < n_nodes) {
        const float* p = &s_part[nodeLocal][lane * 8];
        #pragma unroll
        for (int j = 0; j < 8; ++j) acc[j] += p[j];
        ssum += s_part[nodeLocal][32];
        float inv_s = (ssum > 0.f) ? (1.0f / ssum) : 0.0f;
        float* op = out + (size_t)myv * D_FEAT + lane * 8;
        reinterpret_cast<float4*>(op)[0] =
            make_float4(acc[0] * inv_s, acc[1] * inv_s, acc[2] * inv_s, acc[3] * inv_s);
        reinterpret_cast<float4*>(op)[1] =
            make_float4(acc[4] * inv_s, acc[5] * inv_s, acc[6] * inv_s, acc[7] * inv_s);
    }
}

// ---------------------------------------------------------------------------
// Fallback 1 (proven R6): packed linked-list + bf16 chase.
// ---------------------------------------------------------------------------
__global__ void prep_kernel(const float* __restrict__ feat,
                            unsigned short* __restrict__ nfb,
                            float* __restrict__ inv_norm, int n_nodes) {
    int g = blockIdx.x * blockDim.x + threadIdx.x;
    int node = g >> 3;
    int lane = g & 7;
    if (node >= n_nodes) return;
    float4 v = reinterpret_cast<const float4*>(feat + (size_t)node * D_FEAT)[lane];
    float ss = v.x * v.x + v.y * v.y + v.z * v.z + v.w * v.w;
    #pragma unroll
    for (int m = 4; m; m >>= 1) ss += __shfl_xor(ss, m, 8);
    if (lane == 0) inv_norm[node] = 1.0f / fmaxf(sqrtf(ss), 1e-12f);
    ushort4 b;
    b.x = f2bf(v.x); b.y = f2bf(v.y); b.z = f2bf(v.z); b.w = f2bf(v.w);
    reinterpret_cast<ushort4*>(nfb + (size_t)node * D_FEAT)[lane] = b;
}

__global__ void link_packed_kernel(const int* __restrict__ src,
                                   const int* __restrict__ dst,
                                   int* __restrict__ head,
                                   int2* __restrict__ rec, int n_edges) {
    int stride = gridDim.x * blockDim.x;
    for (int e = blockIdx.x * blockDim.x + threadIdx.x; e < n_edges; e += stride) {
        int d = dst[e];
        int s = src[e];
        int old = atomicExch(&head[d], e);
        rec[e] = make_int2(old, s);
    }
}

__global__ void fused_chase_bf16_kernel(const unsigned short* __restrict__ nfb,
                                        const float* __restrict__ inv_norm,
                                        const int* __restrict__ head,
                                        const int2* __restrict__ rec,
                                        const float* __restrict__ beta,
                                        float* __restrict__ out, int n_nodes) {
    int g = blockIdx.x * blockDim.x + threadIdx.x;
    int node = g >> 2;
    int lane = g & 3;
    if (node >= n_nodes) return;

    float bscale = beta[0];
    float invv = inv_norm[node];
    u16x8 braw = reinterpret_cast<const u16x8*>(nfb + (size_t)node * D_FEAT)[lane];
    f32x8 bn;
    #pragma unroll
    for (int j = 0; j < 8; ++j) bn[j] = bf2f(braw[j]) * invv;

    f32x8 acc;
    #pragma unroll
    for (int j = 0; j < 8; ++j) acc[j] = 0.f;
    float ssum = 0.f;

    int e = head[node];
    while (e >= 0) {
        int2 r = rec[e];
        int en = r.x, u = r.y;
        float invu = inv_norm[u];
        u16x8 araw = reinterpret_cast<const u16x8*>(nfb + (size_t)u * D_FEAT)[lane];
        f32x8 a;
        float d = 0.f;
        #pragma unroll
        for (int j = 0; j < 8; ++j) {
            a[j] = bf2f(araw[j]);
            d = fmaf(a[j], bn[j], d);
        }
        d += __shfl_xor(d, 1, 4);
        d += __shfl_xor(d, 2, 4);
        float pe = __expf(bscale * d * invu);
        #pragma unroll
        for (int j = 0; j < 8; ++j) acc[j] = fmaf(pe, a[j], acc[j]);
        ssum += pe;
        e = en;
    }

    float inv_s = (ssum > 0.f) ? (1.0f / ssum) : 0.0f;
    float* op = out + (size_t)node * D_FEAT + lane * 8;
    reinterpret_cast<float4*>(op)[0] =
        make_float4(acc[0] * inv_s, acc[1] * inv_s, acc[2] * inv_s, acc[3] * inv_s);
    reinterpret_cast<float4*>(op)[1] =
        make_float4(acc[4] * inv_s, acc[5] * inv_s, acc[6] * inv_s, acc[7] * inv_s);
}

// ---------------------------------------------------------------------------
// Fallback 2 (tiny ws): f32 atomic path.
// ---------------------------------------------------------------------------
__global__ void node_invnorm_kernel(const float* __restrict__ feat,
                                    float* __restrict__ inv_norm, int n_nodes) {
    int g = blockIdx.x * blockDim.x + threadIdx.x;
    int node = g >> 3;
    int lane = g & 7;
    if (node >= n_nodes) return;
    float4 v = reinterpret_cast<const float4*>(feat + (size_t)node * D_FEAT)[lane];
    float ss = v.x * v.x + v.y * v.y + v.z * v.z + v.w * v.w;
    #pragma unroll
    for (int m = 4; m; m >>= 1) ss += __shfl_xor(ss, m, 8);
    if (lane == 0) inv_norm[node] = 1.0f / fmaxf(sqrtf(ss), 1e-12f);
}

__global__ void edge_p_kernel(const float* __restrict__ feat,
                              const float* __restrict__ inv_norm,
                              const int* __restrict__ src,
                              const int* __restrict__ dst,
                              const float* __restrict__ beta,
                              float* __restrict__ p, float* __restrict__ s,
                              int n_edges) {
    int g = blockIdx.x * blockDim.x + threadIdx.x;
    int e = g >> 3;
    int lane = g & 7;
    if (e >= n_edges) return;
    int u = src[e];
    int v = dst[e];
    float4 a = reinterpret_cast<const float4*>(feat + (size_t)u * D_FEAT)[lane];
    float4 b = reinterpret_cast<const float4*>(feat + (size_t)v * D_FEAT)[lane];
    float d = a.x * b.x;
    d = fmaf(a.y, b.y, d);
    d = fmaf(a.z, b.z, d);
    d = fmaf(a.w, b.w, d);
    #pragma unroll
    for (int m = 4; m; m >>= 1) d += __shfl_xor(d, m, 8);
    if (lane == 0) {
        float pe = __expf(beta[0] * d * inv_norm[u] * inv_norm[v]);
        p[e] = pe;
        atomicAdd(&s[v], pe);
    }
}

__global__ void aggregate_atomic_kernel(const float* __restrict__ feat,
                                        const int* __restrict__ src,
                                        const int* __restrict__ dst,
                                        const float* __restrict__ p,
                                        const float* __restrict__ s,
                                        float* __restrict__ out, int n_edges) {
    int g = blockIdx.x * blockDim.x + threadIdx.x;
    int e = g >> 5;
    int lane = g & 31;
    if (e >= n_edges) return;
    int u = src[e];
    int v = dst[e];
    float w = p[e] / s[v];
    atomicAdd(&out[(size_t)v * D_FEAT + lane], feat[(size_t)u * D_FEAT + lane] * w);
}

extern "C" void kernel_launch(void* const* d_in, const int* in_sizes, int n_in,
                              void* d_out, int out_size, void* d_ws, size_t ws_size,
                              hipStream_t stream) {
    const float* feat = (const float*)d_in[0];
    const float* beta = (const float*)d_in[1];
    const int*   src  = (const int*)d_in[2];
    const int*   dst  = (const int*)d_in[3];
    float* out = (float*)d_out;

    int n_nodes = in_sizes[0] / D_FEAT;
    int n_edges = in_sizes[2];
    int nb = (n_nodes + BUCKET_NODES - 1) / BUCKET_NODES;
    int nchunk = (n_edges + CHUNK_E - 1) / CHUNK_E;

    size_t nfb_bytes = (size_t)n_nodes * D_FEAT * 2;
    size_t need_sort = nfb_bytes +
                       ((size_t)n_nodes + (nb + 1) + MAX_NB +
                        (size_t)nb * nchunk + (size_t)n_edges) * 4;
    size_t need_ll = nfb_bytes + (size_t)n_nodes * 8 + (size_t)n_edges * 8;

    bool sort_ok = (ws_size >= need_sort) && (nb <= MAX_NB) &&
                   (n_nodes <= (1 << 24));

    if (sort_ok) {
        unsigned short* nfb = (unsigned short*)d_ws;
        float* inv_norm   = (float*)((char*)d_ws + nfb_bytes);
        int* bucket_base  = (int*)(inv_norm + n_nodes);   // [nb]; alloc at [nb]
        int* alloc        = bucket_base + nb;
        int* total        = bucket_base + (nb + 1);
        int* chunk_hist   = total + MAX_NB;
        int* recs         = chunk_hist + (size_t)nb * nchunk;

        {
            int prep_blocks = (n_nodes * 8 + 255) / 256;
            prep_hist_kernel<<<nchunk + prep_blocks, 256, 0, stream>>>(
                feat, nfb, inv_norm, dst, chunk_hist, alloc,
                n_nodes, n_edges, nb, nchunk);
        }
        {
            int blocks = (nb + 3) / 4;
            col_prefix_kernel<<<blocks, 256, 0, stream>>>(
                chunk_hist, total, bucket_base, alloc, nchunk, nb);
        }
        scatter_kernel<<<nchunk, 512, 0, stream>>>(src, dst, chunk_hist, bucket_base,
                                                   recs, n_edges, nb, nchunk);
        bucket_aggregate_kernel<<<nb * 2, 512, 0, stream>>>(
            nfb, inv_norm, bucket_base, total, recs, beta, out, n_nodes);
    } else if (ws_size >= need_ll) {
        unsigned short* nfb = (unsigned short*)d_ws;
        float* inv_norm = (float*)((char*)d_ws + nfb_bytes);
        int*   head     = (int*)(inv_norm + n_nodes);
        int2*  rec      = (int2*)(head + n_nodes);

        hipMemsetAsync(head, 0xFF, (size_t)n_nodes * sizeof(int), stream);
        {
            int tt = n_nodes * 8;
            prep_kernel<<<(tt + 255) / 256, 256, 0, stream>>>(feat, nfb, inv_norm, n_nodes);
        }
        link_packed_kernel<<<2048, 256, 0, stream>>>(src, dst, head, rec, n_edges);
        {
            int tt = n_nodes * 4;
            fused_chase_bf16_kernel<<<(tt + 255) / 256, 256, 0, stream>>>(
                nfb, inv_norm, head, rec, beta, out, n_nodes);
        }
    } else {
        float* inv_norm = (float*)d_ws;
        float* s_sum    = inv_norm + n_nodes;
        float* p        = s_sum + n_nodes;

        hipMemsetAsync(s_sum, 0, (size_t)n_nodes * sizeof(float), stream);
        hipMemsetAsync(out, 0, (size_t)out_size * sizeof(float), stream);

        {
            int tt = n_nodes * 8;
            node_invnorm_kernel<<<(tt + 255) / 256, 256, 0, stream>>>(feat, inv_norm, n_nodes);
        }
        {
            long long tt = (long long)n_edges * 8;
            edge_p_kernel<<<(int)((tt + 255) / 256), 256, 0, stream>>>(
                feat, inv_norm, src, dst, beta, p, s_sum, n_edges);
        }
        {
            long long tt = (long long)n_edges * 32;
            aggregate_atomic_kernel<<<(int)((tt + 255) / 256), 256, 0, stream>>>(
                feat, src, dst, p, s_sum, out, n_edges);
        }
    }
}

// Round 19
// 65.271 us; speedup vs baseline: 1.2784x; 1.0998x over previous
//
#include <hip/hip_runtime.h>
#include <hip/hip_bf16.h>

#define D_FEAT 32
#define BUCKET_SHIFT 7
#define BUCKET_NODES 128           // 1 << BUCKET_SHIFT
#define MAX_NB 1024                // max buckets
#define CHUNK_E 8192               // edges per sort chunk (62KB LDS in scatter)
#define REC_CHUNK 4096             // records staged per aggregate chunk (=512*8)

typedef __attribute__((ext_vector_type(8))) unsigned short u16x8;
typedef __attribute__((ext_vector_type(8))) float f32x8;

// round-to-nearest-even f32 -> bf16 bits
static __device__ __forceinline__ unsigned short f2bf(float x) {
    unsigned int u = __float_as_uint(x);
    u += 0x7FFFu + ((u >> 16) & 1u);
    return (unsigned short)(u >> 16);
}
static __device__ __forceinline__ float bf2f(unsigned short b) {
    return __uint_as_float((unsigned int)b << 16);
}

// ---------------------------------------------------------------------------
// K0 (fused): blocks [0, nchunk) do the per-chunk bucket histogram (int4
// vectorized); blocks [nchunk, ...) do prep (inv_norm + bf16 row compress).
// ---------------------------------------------------------------------------
__global__ __launch_bounds__(256) void prep_hist_kernel(
    const float* __restrict__ feat,
    unsigned short* __restrict__ nfb,
    float* __restrict__ inv_norm,
    const int* __restrict__ dst,
    int* __restrict__ chunk_hist,
    int n_nodes, int n_edges, int nb, int nchunk) {

    __shared__ int s_h[MAX_NB];
    int bid = blockIdx.x;
    int t = threadIdx.x;

    if (bid < nchunk) {
        for (int i = t; i < MAX_NB; i += 256) s_h[i] = 0;
        __syncthreads();
        int base = bid * CHUNK_E;
        int cnt = min(CHUNK_E, n_edges - base);
        int cnt4 = cnt >> 2;
        const int4* dst4 = reinterpret_cast<const int4*>(dst + base);
        for (int k = t; k < cnt4; k += 256) {
            int4 d4 = dst4[k];
            atomicAdd(&s_h[d4.x >> BUCKET_SHIFT], 1);
            atomicAdd(&s_h[d4.y >> BUCKET_SHIFT], 1);
            atomicAdd(&s_h[d4.z >> BUCKET_SHIFT], 1);
            atomicAdd(&s_h[d4.w >> BUCKET_SHIFT], 1);
        }
        for (int k = (cnt4 << 2) + t; k < cnt; k += 256)
            atomicAdd(&s_h[dst[base + k] >> BUCKET_SHIFT], 1);
        __syncthreads();
        for (int i = t; i < nb; i += 256)
            chunk_hist[(size_t)i * nchunk + bid] = s_h[i];
    } else {
        int g = (bid - nchunk) * 256 + t;
        int node = g >> 3;
        int lane = g & 7;
        if (node >= n_nodes) return;
        float4 v = reinterpret_cast<const float4*>(feat + (size_t)node * D_FEAT)[lane];
        float ss = v.x * v.x + v.y * v.y + v.z * v.z + v.w * v.w;
        #pragma unroll
        for (int m = 4; m; m >>= 1) ss += __shfl_xor(ss, m, 8);
        if (lane == 0) inv_norm[node] = 1.0f / fmaxf(sqrtf(ss), 1e-12f);
        ushort4 b;
        b.x = f2bf(v.x); b.y = f2bf(v.y); b.z = f2bf(v.z); b.w = f2bf(v.w);
        reinterpret_cast<ushort4*>(nfb + (size_t)node * D_FEAT)[lane] = b;
    }
}

// ---------------------------------------------------------------------------
// S2: per-bucket prefix over chunks — ONE WAVE per bucket.
// ---------------------------------------------------------------------------
__global__ void col_prefix_kernel(int* __restrict__ chunk_hist,
                                  int* __restrict__ total, int nchunk, int nb) {
    int wid  = (blockIdx.x * blockDim.x + threadIdx.x) >> 6;
    int lane = threadIdx.x & 63;
    if (wid >= nb) return;
    int* row = chunk_hist + (size_t)wid * nchunk;
    int run = 0;
    for (int base = 0; base < nchunk; base += 64) {
        int c = base + lane;
        int v = (c < nchunk) ? row[c] : 0;
        int incl = v;
        #pragma unroll
        for (int off = 1; off < 64; off <<= 1) {
            int n = __shfl_up(incl, off, 64);
            if (lane >= off) incl += n;
        }
        if (c < nchunk) row[c] = run + (incl - v);   // exclusive within bucket
        run += __shfl(incl, 63, 64);                 // carry (uniform)
    }
    if (lane == 0) total[wid] = run;
}

// ---------------------------------------------------------------------------
// S3: single-block exclusive scan of bucket totals (4 items/thread, 1024 max).
// Ordered regions give the aggregate cross-block L2 locality on recs — this
// 1.5us kernel pays for itself (allocator variant measured +6us, R18).
// ---------------------------------------------------------------------------
__global__ __launch_bounds__(256) void base_scan_kernel(const int* __restrict__ total,
                                                        int* __restrict__ bucket_base,
                                                        int nb, int n_edges) {
    __shared__ int s_sum[256];
    int t = threadIdx.x;
    int i0 = t * 4;
    int a[4];
    int tsum = 0;
    #pragma unroll
    for (int j = 0; j < 4; ++j) {
        a[j] = (i0 + j < nb) ? total[i0 + j] : 0;
        tsum += a[j];
    }
    s_sum[t] = tsum;
    __syncthreads();
    for (int off = 1; off < 256; off <<= 1) {
        int add = (t >= off) ? s_sum[t - off] : 0;
        __syncthreads();
        s_sum[t] += add;
        __syncthreads();
    }
    int run = s_sum[t] - tsum;
    #pragma unroll
    for (int j = 0; j < 4; ++j) {
        if (i0 + j < nb) bucket_base[i0 + j] = run;
        run += a[j];
    }
    if (t == 0) bucket_base[nb] = n_edges;
}

// ---------------------------------------------------------------------------
// S4: scatter @512 threads. Per chunk (8192 edges): LDS counting sort by
// bucket (int4 index reads), copy runs to precomputed global slots.
// Zero global atomics. LDS ~62KB.
// ---------------------------------------------------------------------------
__global__ __launch_bounds__(512) void scatter_kernel(const int* __restrict__ src,
                                                      const int* __restrict__ dst,
                                                      const int* __restrict__ chunk_hist,
                                                      const int* __restrict__ bucket_base,
                                                      int* __restrict__ recs,
                                                      int n_edges, int nb, int nchunk) {
    __shared__ int s_cur[MAX_NB];
    __shared__ int s_off[MAX_NB + 1];
    __shared__ int s_gbase[MAX_NB];
    __shared__ int s_sum[512];
    __shared__ int s_rec[CHUNK_E];
    __shared__ unsigned short s_b[CHUNK_E];

    int c = blockIdx.x;
    int t = threadIdx.x;
    int base = c * CHUNK_E;
    int cnt = min(CHUNK_E, n_edges - base);
    int cnt4 = cnt >> 2;
    const int4* dst4 = reinterpret_cast<const int4*>(dst + base);
    const int4* src4 = reinterpret_cast<const int4*>(src + base);

    for (int i = t; i < MAX_NB; i += 512) s_cur[i] = 0;
    __syncthreads();
    for (int k = t; k < cnt4; k += 512) {
        int4 d4 = dst4[k];
        atomicAdd(&s_cur[d4.x >> BUCKET_SHIFT], 1);
        atomicAdd(&s_cur[d4.y >> BUCKET_SHIFT], 1);
        atomicAdd(&s_cur[d4.z >> BUCKET_SHIFT], 1);
        atomicAdd(&s_cur[d4.w >> BUCKET_SHIFT], 1);
    }
    for (int k = (cnt4 << 2) + t; k < cnt; k += 512)
        atomicAdd(&s_cur[dst[base + k] >> BUCKET_SHIFT], 1);
    __syncthreads();

    // exclusive scan of s_cur[1024] -> s_off (2 items/thread, 512 threads)
    int i0 = t * 2;
    int a0 = s_cur[i0], a1 = s_cur[i0 + 1];
    int tsum = a0 + a1;
    s_sum[t] = tsum;
    __syncthreads();
    for (int off = 1; off < 512; off <<= 1) {
        int add = (t >= off) ? s_sum[t - off] : 0;
        __syncthreads();
        s_sum[t] += add;
        __syncthreads();
    }
    int run = s_sum[t] - tsum;
    s_off[i0] = run;
    s_off[i0 + 1] = run + a0;
    if (t == 511) s_off[MAX_NB] = run + tsum;  // == cnt
    __syncthreads();
    for (int i = t; i < MAX_NB; i += 512) s_cur[i] = s_off[i];
    for (int i = t; i < nb; i += 512)
        s_gbase[i] = bucket_base[i] + chunk_hist[(size_t)i * nchunk + c];
    __syncthreads();

    for (int k = t; k < cnt4; k += 512) {
        int4 d4 = dst4[k];
        int4 s4 = src4[k];
        #pragma unroll
        for (int j = 0; j < 4; ++j) {
            int d = (j == 0) ? d4.x : (j == 1) ? d4.y : (j == 2) ? d4.z : d4.w;
            int s = (j == 0) ? s4.x : (j == 1) ? s4.y : (j == 2) ? s4.z : s4.w;
            int bb = d >> BUCKET_SHIFT;
            int lpos = atomicAdd(&s_cur[bb], 1);
            s_rec[lpos] = (s << BUCKET_SHIFT) | (d & (BUCKET_NODES - 1));
            s_b[lpos] = (unsigned short)bb;
        }
    }
    for (int k = (cnt4 << 2) + t; k < cnt; k += 512) {
        int d = dst[base + k];
        int s = src[base + k];
        int bb = d >> BUCKET_SHIFT;
        int lpos = atomicAdd(&s_cur[bb], 1);
        s_rec[lpos] = (s << BUCKET_SHIFT) | (d & (BUCKET_NODES - 1));
        s_b[lpos] = (unsigned short)bb;
    }
    __syncthreads();

    for (int i = t; i < cnt; i += 512) {
        int bb = s_b[i];
        recs[s_gbase[bb] + (i - s_off[bb])] = s_rec[i];
    }
}

// ---------------------------------------------------------------------------
// C v6 (best measured, R16): TWO blocks per bucket (grid nb*2) — each block
// owns 64 nodes and each node's run is split across TWO groups (even/odd
// records). 512 thr = 128 groups x 4 lanes; group g -> node (g&63),
// subsequence (g>>6). Records reg-staged once; hist/placement filtered to
// this block's half (64 counters, wave-0 scan). Partials combined via LDS;
// single coalesced row write per node.
// ---------------------------------------------------------------------------
__global__ __launch_bounds__(512) void bucket_aggregate_kernel(
    const unsigned short* __restrict__ nfb,
    const float* __restrict__ inv_norm,
    const int* __restrict__ bucket_base,
    const int* __restrict__ recs,
    const float* __restrict__ beta,
    float* __restrict__ out, int n_nodes) {

    __shared__ int s_rec[REC_CHUNK];          // 16 KB (<= half used)
    __shared__ int s_hist[64];
    __shared__ int s_off[65];
    __shared__ float s_part[64][36];          // partial acc[32] + ssum@32, 9.2 KB

    int blk = blockIdx.x;
    int b    = blk >> 1;       // bucket
    int half = blk & 1;        // which 64-node half of the bucket
    int node0 = b * BUCKET_NODES + half * 64;
    int start = bucket_base[b];
    int end   = bucket_base[b + 1];
    int t = threadIdx.x;
    int group = t >> 2;        // 0..127
    int lane  = t & 3;         // 16B of the 64B row per lane
    int nodeLocal = group & 63;
    int sub = group >> 6;      // 0: even records, 1: odd records
    float bscale = beta[0];

    int myv = node0 + nodeLocal;
    f32x8 bn;
    f32x8 acc;
    float ssum = 0.f;
    #pragma unroll
    for (int j = 0; j < 8; ++j) { bn[j] = 0.f; acc[j] = 0.f; }
    if (myv < n_nodes) {
        u16x8 braw = reinterpret_cast<const u16x8*>(nfb + (size_t)myv * D_FEAT)[lane];
        float invv = inv_norm[myv];
        #pragma unroll
        for (int j = 0; j < 8; ++j) bn[j] = bf2f(braw[j]) * invv;
    }

    for (int cbase = start; cbase < end; cbase += REC_CHUNK) {
        int cnt = min(REC_CHUNK, end - cbase);

        // single global read of this chunk's records into registers
        int r[8];
        #pragma unroll
        for (int j = 0; j < 8; ++j) {
            int k = t + j * 512;                 // coalesced stride-512
            r[j] = (k < cnt) ? recs[cbase + k] : -1;
        }

        if (t < 64) s_hist[t] = 0;
        __syncthreads();
        #pragma unroll
        for (int j = 0; j < 8; ++j)
            if (r[j] >= 0) {
                int dl = r[j] & (BUCKET_NODES - 1);
                if ((dl >> 6) == half) atomicAdd(&s_hist[dl & 63], 1);
            }
        __syncthreads();

        // wave-0 shuffle scan of the 64 counters
        if (t < 64) {
            int v = s_hist[t];
            int incl = v;
            #pragma unroll
            for (int off = 1; off < 64; off <<= 1) {
                int n = __shfl_up(incl, off, 64);
                if (t >= off) incl += n;
            }
            s_off[t + 1] = incl;
            if (t == 0) s_off[0] = 0;
            s_hist[t] = incl - v;   // run cursor (exclusive start)
        }
        __syncthreads();

        #pragma unroll
        for (int j = 0; j < 8; ++j)
            if (r[j] >= 0) {
                int dl = r[j] & (BUCKET_NODES - 1);
                if ((dl >> 6) == half) {
                    int pos = atomicAdd(&s_hist[dl & 63], 1);
                    s_rec[pos] = r[j];
                }
            }
        __syncthreads();

        // walk my node's subsequence (records rs+sub, step 2), 2-deep pipeline
        {
            int rs = s_off[nodeLocal];
            int re = s_off[nodeLocal + 1];
            int i = rs + sub;

            int u0 = 0; float inv0 = 0.f;
            u16x8 raw0;
            #pragma unroll
            for (int j = 0; j < 8; ++j) raw0[j] = 0;
            if (i < re) {
                u0 = ((unsigned)s_rec[i]) >> BUCKET_SHIFT;
                inv0 = inv_norm[u0];
                raw0 = reinterpret_cast<const u16x8*>(nfb + (size_t)u0 * D_FEAT)[lane];
            }
            for (; i < re; i += 2) {
                int u1 = 0; float inv1 = 0.f;
                u16x8 raw1;
                #pragma unroll
                for (int j = 0; j < 8; ++j) raw1[j] = 0;
                if (i + 2 < re) {
                    u1 = ((unsigned)s_rec[i + 2]) >> BUCKET_SHIFT;
                    inv1 = inv_norm[u1];
                    raw1 = reinterpret_cast<const u16x8*>(nfb + (size_t)u1 * D_FEAT)[lane];
                }
                f32x8 a;
                float d = 0.f;
                #pragma unroll
                for (int j = 0; j < 8; ++j) {
                    a[j] = bf2f(raw0[j]);
                    d = fmaf(a[j], bn[j], d);
                }
                d += __shfl_xor(d, 1, 4);
                d += __shfl_xor(d, 2, 4);
                float pe = __expf(bscale * d * inv0);  // |arg|<=beta: no max-shift
                #pragma unroll
                for (int j = 0; j < 8; ++j) acc[j] = fmaf(pe, a[j], acc[j]);
                ssum += pe;
                raw0 = raw1; inv0 = inv1;
            }
        }
        __syncthreads();
    }

    // combine sub0 + sub1 partials via LDS, then write
    if (sub == 0) {
        float* p = &s_part[nodeLocal][lane * 8];
        #pragma unroll
        for (int j = 0; j < 8; ++j) p[j] = acc[j];
        if (lane == 0) s_part[nodeLocal][32] = ssum;
    }
    __syncthreads();
    if (sub == 1 && myv < n_nodes) {
        const float* p = &s_part[nodeLocal][lane * 8];
        #pragma unroll
        for (int j = 0; j < 8; ++j) acc[j] += p[j];
        ssum += s_part[nodeLocal][32];
        float inv_s = (ssum > 0.f) ? (1.0f / ssum) : 0.0f;
        float* op = out + (size_t)myv * D_FEAT + lane * 8;
        reinterpret_cast<float4*>(op)[0] =
            make_float4(acc[0] * inv_s, acc[1] * inv_s, acc[2] * inv_s, acc[3] * inv_s);
        reinterpret_cast<float4*>(op)[1] =
            make_float4(acc[4] * inv_s, acc[5] * inv_s, acc[6] * inv_s, acc[7] * inv_s);
    }
}

// ---------------------------------------------------------------------------
// Fallback 1 (proven R6): packed linked-list + bf16 chase.
// ---------------------------------------------------------------------------
__global__ void prep_kernel(const float* __restrict__ feat,
                            unsigned short* __restrict__ nfb,
                            float* __restrict__ inv_norm, int n_nodes) {
    int g = blockIdx.x * blockDim.x + threadIdx.x;
    int node = g >> 3;
    int lane = g & 7;
    if (node >= n_nodes) return;
    float4 v = reinterpret_cast<const float4*>(feat + (size_t)node * D_FEAT)[lane];
    float ss = v.x * v.x + v.y * v.y + v.z * v.z + v.w * v.w;
    #pragma unroll
    for (int m = 4; m; m >>= 1) ss += __shfl_xor(ss, m, 8);
    if (lane == 0) inv_norm[node] = 1.0f / fmaxf(sqrtf(ss), 1e-12f);
    ushort4 b;
    b.x = f2bf(v.x); b.y = f2bf(v.y); b.z = f2bf(v.z); b.w = f2bf(v.w);
    reinterpret_cast<ushort4*>(nfb + (size_t)node * D_FEAT)[lane] = b;
}

__global__ void link_packed_kernel(const int* __restrict__ src,
                                   const int* __restrict__ dst,
                                   int* __restrict__ head,
                                   int2* __restrict__ rec, int n_edges) {
    int stride = gridDim.x * blockDim.x;
    for (int e = blockIdx.x * blockDim.x + threadIdx.x; e < n_edges; e += stride) {
        int d = dst[e];
        int s = src[e];
        int old = atomicExch(&head[d], e);
        rec[e] = make_int2(old, s);
    }
}

__global__ void fused_chase_bf16_kernel(const unsigned short* __restrict__ nfb,
                                        const float* __restrict__ inv_norm,
                                        const int* __restrict__ head,
                                        const int2* __restrict__ rec,
                                        const float* __restrict__ beta,
                                        float* __restrict__ out, int n_nodes) {
    int g = blockIdx.x * blockDim.x + threadIdx.x;
    int node = g >> 2;
    int lane = g & 3;
    if (node >= n_nodes) return;

    float bscale = beta[0];
    float invv = inv_norm[node];
    u16x8 braw = reinterpret_cast<const u16x8*>(nfb + (size_t)node * D_FEAT)[lane];
    f32x8 bn;
    #pragma unroll
    for (int j = 0; j < 8; ++j) bn[j] = bf2f(braw[j]) * invv;

    f32x8 acc;
    #pragma unroll
    for (int j = 0; j < 8; ++j) acc[j] = 0.f;
    float ssum = 0.f;

    int e = head[node];
    while (e >= 0) {
        int2 r = rec[e];
        int en = r.x, u = r.y;
        float invu = inv_norm[u];
        u16x8 araw = reinterpret_cast<const u16x8*>(nfb + (size_t)u * D_FEAT)[lane];
        f32x8 a;
        float d = 0.f;
        #pragma unroll
        for (int j = 0; j < 8; ++j) {
            a[j] = bf2f(araw[j]);
            d = fmaf(a[j], bn[j], d);
        }
        d += __shfl_xor(d, 1, 4);
        d += __shfl_xor(d, 2, 4);
        float pe = __expf(bscale * d * invu);
        #pragma unroll
        for (int j = 0; j < 8; ++j) acc[j] = fmaf(pe, a[j], acc[j]);
        ssum += pe;
        e = en;
    }

    float inv_s = (ssum > 0.f) ? (1.0f / ssum) : 0.0f;
    float* op = out + (size_t)node * D_FEAT + lane * 8;
    reinterpret_cast<float4*>(op)[0] =
        make_float4(acc[0] * inv_s, acc[1] * inv_s, acc[2] * inv_s, acc[3] * inv_s);
    reinterpret_cast<float4*>(op)[1] =
        make_float4(acc[4] * inv_s, acc[5] * inv_s, acc[6] * inv_s, acc[7] * inv_s);
}

// ---------------------------------------------------------------------------
// Fallback 2 (tiny ws): f32 atomic path.
// ---------------------------------------------------------------------------
__global__ void node_invnorm_kernel(const float* __restrict__ feat,
                                    float* __restrict__ inv_norm, int n_nodes) {
    int g = blockIdx.x * blockDim.x + threadIdx.x;
    int node = g >> 3;
    int lane = g & 7;
    if (node >= n_nodes) return;
    float4 v = reinterpret_cast<const float4*>(feat + (size_t)node * D_FEAT)[lane];
    float ss = v.x * v.x + v.y * v.y + v.z * v.z + v.w * v.w;
    #pragma unroll
    for (int m = 4; m; m >>= 1) ss += __shfl_xor(ss, m, 8);
    if (lane == 0) inv_norm[node] = 1.0f / fmaxf(sqrtf(ss), 1e-12f);
}

__global__ void edge_p_kernel(const float* __restrict__ feat,
                              const float* __restrict__ inv_norm,
                              const int* __restrict__ src,
                              const int* __restrict__ dst,
                              const float* __restrict__ beta,
                              float* __restrict__ p, float* __restrict__ s,
                              int n_edges) {
    int g = blockIdx.x * blockDim.x + threadIdx.x;
    int e = g >> 3;
    int lane = g & 7;
    if (e >= n_edges) return;
    int u = src[e];
    int v = dst[e];
    float4 a = reinterpret_cast<const float4*>(feat + (size_t)u * D_FEAT)[lane];
    float4 b = reinterpret_cast<const float4*>(feat + (size_t)v * D_FEAT)[lane];
    float d = a.x * b.x;
    d = fmaf(a.y, b.y, d);
    d = fmaf(a.z, b.z, d);
    d = fmaf(a.w, b.w, d);
    #pragma unroll
    for (int m = 4; m; m >>= 1) d += __shfl_xor(d, m, 8);
    if (lane == 0) {
        float pe = __expf(beta[0] * d * inv_norm[u] * inv_norm[v]);
        p[e] = pe;
        atomicAdd(&s[v], pe);
    }
}

__global__ void aggregate_atomic_kernel(const float* __restrict__ feat,
                                        const int* __restrict__ src,
                                        const int* __restrict__ dst,
                                        const float* __restrict__ p,
                                        const float* __restrict__ s,
                                        float* __restrict__ out, int n_edges) {
    int g = blockIdx.x * blockDim.x + threadIdx.x;
    int e = g >> 5;
    int lane = g & 31;
    if (e >= n_edges) return;
    int u = src[e];
    int v = dst[e];
    float w = p[e] / s[v];
    atomicAdd(&out[(size_t)v * D_FEAT + lane], feat[(size_t)u * D_FEAT + lane] * w);
}

extern "C" void kernel_launch(void* const* d_in, const int* in_sizes, int n_in,
                              void* d_out, int out_size, void* d_ws, size_t ws_size,
                              hipStream_t stream) {
    const float* feat = (const float*)d_in[0];
    const float* beta = (const float*)d_in[1];
    const int*   src  = (const int*)d_in[2];
    const int*   dst  = (const int*)d_in[3];
    float* out = (float*)d_out;

    int n_nodes = in_sizes[0] / D_FEAT;
    int n_edges = in_sizes[2];
    int nb = (n_nodes + BUCKET_NODES - 1) / BUCKET_NODES;
    int nchunk = (n_edges + CHUNK_E - 1) / CHUNK_E;

    size_t nfb_bytes = (size_t)n_nodes * D_FEAT * 2;
    size_t need_sort = nfb_bytes +
                       ((size_t)n_nodes + (nb + 1) + MAX_NB +
                        (size_t)nb * nchunk + (size_t)n_edges) * 4;
    size_t need_ll = nfb_bytes + (size_t)n_nodes * 8 + (size_t)n_edges * 8;

    bool sort_ok = (ws_size >= need_sort) && (nb <= MAX_NB) &&
                   (n_nodes <= (1 << 24));

    if (sort_ok) {
        unsigned short* nfb = (unsigned short*)d_ws;
        float* inv_norm   = (float*)((char*)d_ws + nfb_bytes);
        int* bucket_base  = (int*)(inv_norm + n_nodes);
        int* total        = bucket_base + (nb + 1);
        int* chunk_hist   = total + MAX_NB;
        int* recs         = chunk_hist + (size_t)nb * nchunk;

        {
            int prep_blocks = (n_nodes * 8 + 255) / 256;
            prep_hist_kernel<<<nchunk + prep_blocks, 256, 0, stream>>>(
                feat, nfb, inv_norm, dst, chunk_hist, n_nodes, n_edges, nb, nchunk);
        }
        {
            int blocks = (nb + 3) / 4;
            col_prefix_kernel<<<blocks, 256, 0, stream>>>(chunk_hist, total, nchunk, nb);
        }
        base_scan_kernel<<<1, 256, 0, stream>>>(total, bucket_base, nb, n_edges);
        scatter_kernel<<<nchunk, 512, 0, stream>>>(src, dst, chunk_hist, bucket_base,
                                                   recs, n_edges, nb, nchunk);
        bucket_aggregate_kernel<<<nb * 2, 512, 0, stream>>>(
            nfb, inv_norm, bucket_base, recs, beta, out, n_nodes);
    } else if (ws_size >= need_ll) {
        unsigned short* nfb = (unsigned short*)d_ws;
        float* inv_norm = (float*)((char*)d_ws + nfb_bytes);
        int*   head     = (int*)(inv_norm + n_nodes);
        int2*  rec      = (int2*)(head + n_nodes);

        hipMemsetAsync(head, 0xFF, (size_t)n_nodes * sizeof(int), stream);
        {
            int tt = n_nodes * 8;
            prep_kernel<<<(tt + 255) / 256, 256, 0, stream>>>(feat, nfb, inv_norm, n_nodes);
        }
        link_packed_kernel<<<2048, 256, 0, stream>>>(src, dst, head, rec, n_edges);
        {
            int tt = n_nodes * 4;
            fused_chase_bf16_kernel<<<(tt + 255) / 256, 256, 0, stream>>>(
                nfb, inv_norm, head, rec, beta, out, n_nodes);
        }
    } else {
        float* inv_norm = (float*)d_ws;
        float* s_sum    = inv_norm + n_nodes;
        float* p        = s_sum + n_nodes;

        hipMemsetAsync(s_sum, 0, (size_t)n_nodes * sizeof(float), stream);
        hipMemsetAsync(out, 0, (size_t)out_size * sizeof(float), stream);

        {
            int tt = n_nodes * 8;
            node_invnorm_kernel<<<(tt + 255) / 256, 256, 0, stream>>>(feat, inv_norm, n_nodes);
        }
        {
            long long tt = (long long)n_edges * 8;
            edge_p_kernel<<<(int)((tt + 255) / 256), 256, 0, stream>>>(
                feat, inv_norm, src, dst, beta, p, s_sum, n_edges);
        }
        {
            long long tt = (long long)n_edges * 32;
            aggregate_atomic_kernel<<<(int)((tt + 255) / 256), 256, 0, stream>>>(
                feat, src, dst, p, s_sum, out, n_edges);
        }
    }
}